// Round 7
// baseline (328.773 us; speedup 1.0000x reference)
//
#include <hip/hip_runtime.h>
#include <hip/hip_bf16.h>
#include <stdint.h>

typedef unsigned short u16;
typedef _Float16 f16_t;
typedef f16_t f16x8 __attribute__((ext_vector_type(8)));
typedef u16 u16x8 __attribute__((ext_vector_type(8)));
typedef u16 u16x4 __attribute__((ext_vector_type(4)));
typedef float f32x4 __attribute__((ext_vector_type(4)));

#define L2E 1.44269504088896f
#define DEFER_THR 7.0f

__device__ __forceinline__ u16 f2h(float f) {
  f16_t h = (f16_t)f;
  return __builtin_bit_cast(u16, h);
}
__device__ __forceinline__ f32x4 mfma16h(u16x8 a, u16x8 b, f32x4 c) {
  return __builtin_amdgcn_mfma_f32_16x16x32_f16(
      __builtin_bit_cast(f16x8, a), __builtin_bit_cast(f16x8, b), c, 0, 0, 0);
}
__device__ __forceinline__ void gl16(const u16 *g, u16 *l) {
  __builtin_amdgcn_global_load_lds(
      (const __attribute__((address_space(1))) void *)g,
      (__attribute__((address_space(3))) void *)l, 16, 0, 0);
}

// ---------------- mask normalize (uint8-bool or int32-bool storage) ----------
__global__ void prep_mask_kernel(const unsigned char *__restrict__ mraw,
                                 float *__restrict__ bias) {
  __shared__ int flag;
  int t = threadIdx.x;
  if (t == 0) flag = 0;
  __syncthreads();
  int local = 0;
  for (int i = t; i < 8192; i += 256)
    if ((i & 3) && mraw[i]) local = 1;
  if (local) atomicOr(&flag, 1);
  __syncthreads();
  const bool bytes = (flag != 0);
  const int *mi = (const int *)mraw;
  for (int i = t; i < 8192; i += 256) {
    int m = bytes ? (int)mraw[i] : mi[i];
    bias[i] = m ? -1e30f : 0.0f;
  }
}

// ---------------- f32 -> fp16 convert ---------------------------------------
__global__ void cvt_f16_kernel(const float *__restrict__ in,
                               u16 *__restrict__ out) {
  int i = (blockIdx.x * 256 + threadIdx.x) * 8;
  f32x4 a = *(const f32x4 *)(in + i);
  f32x4 b = *(const f32x4 *)(in + i + 4);
  u16x8 o;
#pragma unroll
  for (int e = 0; e < 4; ++e) {
    o[e] = f2h(a[e]);
    o[4 + e] = f2h(b[e]);
  }
  *(u16x8 *)(out + i) = o;
}

// ---------------- V transpose: vT[b][m][dd][j] = fp16(x2[b][j][m*256+dd]) ----
__global__ void transpose_v_kernel(const float *__restrict__ x2,
                                   u16 *__restrict__ vT) {
  __shared__ float tile[32][33];
  const int b = blockIdx.z, h0 = blockIdx.y * 32, j0 = blockIdx.x * 32;
  const int tx = threadIdx.x & 31, ty = threadIdx.x >> 5; // 32 x 8
#pragma unroll
  for (int rr = 0; rr < 32; rr += 8)
    tile[ty + rr][tx] = x2[((size_t)b * 1024 + j0 + ty + rr) * 1024 + h0 + tx];
  __syncthreads();
  const int mlev = h0 >> 8, dd0 = h0 & 255;
#pragma unroll
  for (int rr = 0; rr < 32; rr += 8) {
    int dd = dd0 + ty + rr;
    vT[((size_t)(b * 4 + mlev) * 256 + dd) * 1024 + j0 + tx] =
        f2h(tile[tx][ty + rr]);
  }
}

// ---------------- fp16 projection GEMM (gllds, depth-3, swapped C-layout) ---
// out = fp16(relu(A*W^T)[*fv]). 128x128 tile, BK=32, 4 waves, 16 MFMA/K-step.
// MFMA computed as mfma(W_frag, x_frag): lane holds 4 consecutive H-cols of
// one M-row -> b64 coalesced stores. 4-buffer LDS, one barrier/iter,
// counted vmcnt (loads get ~3 iterations in flight).
__global__ __launch_bounds__(256, 2) void proj_kernel(
    const u16 *__restrict__ Ag, const u16 *__restrict__ Bg,
    const float *__restrict__ fv, u16 *__restrict__ outk, int usefv) {
  __shared__ u16 As[4][128 * 32], Bs[4][128 * 32]; // 8KB per buf, 64KB total
  const int t = threadIdx.x;
  const int lane = t & 63, wid = t >> 6;
  const int l16 = lane & 15, g = lane >> 4;
  const int wr = wid >> 1, wc = wid & 1; // wr: M-half, wc: H-half
  const int bm = blockIdx.x, bn = blockIdx.y;

  f32x4 acc[4][4] = {}; // [hi][mi]: rows H-cols quad, cols M-row l16

  // gllds lane geometry: rows 32*wid + 16*i + (lane>>2), pre-swizzled source
  const int rA0 = 32 * wid + (lane >> 2), rA1 = rA0 + 16;
  const int cA0 = (lane & 3) ^ ((rA0 >> 1) & 3);
  const int cA1 = (lane & 3) ^ ((rA1 >> 1) & 3);
  const u16 *srcA0 = Ag + (size_t)(bm * 128 + rA0) * 1024 + cA0 * 8;
  const u16 *srcA1 = Ag + (size_t)(bm * 128 + rA1) * 1024 + cA1 * 8;
  const u16 *srcB0 = Bg + (size_t)(bn * 128 + rA0) * 1024 + cA0 * 8;
  const u16 *srcB1 = Bg + (size_t)(bn * 128 + rA1) * 1024 + cA1 * 8;
  const int dst0 = wid * 1024, dst1 = wid * 1024 + 512; // elem offsets

  // prologue: issue tiles 0,1,2
#pragma unroll
  for (int tt = 0; tt < 3; ++tt) {
    const int kel = tt * 32;
    gl16(srcA0 + kel, &As[tt][dst0]);
    gl16(srcA1 + kel, &As[tt][dst1]);
    gl16(srcB0 + kel, &Bs[tt][dst0]);
    gl16(srcB1 + kel, &Bs[tt][dst1]);
  }

  for (int k0 = 0; k0 < 32; ++k0) {
    const int cur = k0 & 3;
    if (k0 <= 29) {
      asm volatile("s_waitcnt vmcnt(8)" ::: "memory");
    } else if (k0 == 30) {
      asm volatile("s_waitcnt vmcnt(4)" ::: "memory");
    } else {
      asm volatile("s_waitcnt vmcnt(0)" ::: "memory");
    }
    __builtin_amdgcn_s_barrier(); // tile k0 fully landed (every wave waited)
    asm volatile("" ::: "memory");
    if (k0 + 3 < 32) { // issue tile k0+3 into buf (k0+3)&3 (reads of it done)
      const int kel = (k0 + 3) * 32, nb = (k0 + 3) & 3;
      gl16(srcA0 + kel, &As[nb][dst0]);
      gl16(srcA1 + kel, &As[nb][dst1]);
      gl16(srcB0 + kel, &Bs[nb][dst0]);
      gl16(srcB1 + kel, &Bs[nb][dst1]);
    }

    u16x8 xf[4], wf[4];
#pragma unroll
    for (int mi = 0; mi < 4; ++mi) {
      int r = wr * 64 + mi * 16 + l16;
      xf[mi] = *(const u16x8 *)(&As[cur][0] + r * 32 + ((g ^ ((r >> 1) & 3)) * 8));
    }
#pragma unroll
    for (int hi = 0; hi < 4; ++hi) {
      int r = wc * 64 + hi * 16 + l16;
      wf[hi] = *(const u16x8 *)(&Bs[cur][0] + r * 32 + ((g ^ ((r >> 1) & 3)) * 8));
    }
#pragma unroll
    for (int hi = 0; hi < 4; ++hi)
#pragma unroll
      for (int mi = 0; mi < 4; ++mi)
        acc[hi][mi] = mfma16h(wf[hi], xf[mi], acc[hi][mi]); // A=W: D rows=H
  }

  // epilogue: lane (g,l16) holds rows H-cols colbase+q, col M-row l16 -> b64
#pragma unroll
  for (int hi = 0; hi < 4; ++hi) {
    const int colbase = bn * 128 + wc * 64 + hi * 16 + g * 4;
    f32x4 fvv;
    if (usefv)
      fvv = *(const f32x4 *)(fv + colbase);
    else
      fvv = (f32x4){1.f, 1.f, 1.f, 1.f};
#pragma unroll
    for (int mi = 0; mi < 4; ++mi) {
      const int row = bm * 128 + wr * 64 + mi * 16 + l16;
      u16x4 o;
#pragma unroll
      for (int q = 0; q < 4; ++q) {
        float v = acc[hi][mi][q];
        v = (v > 0.f ? v : 0.f) * fvv[q];
        o[q] = f2h(v);
      }
      *(u16x4 *)(outk + (size_t)row * 1024 + colbase) = o;
    }
  }
}

// ---------------- fused flash attention (fp16, KVBLK=64, swapped PV) --------
// 512 blocks (2/CU), 4 waves x 16 Q rows. PV computed as mfma(V_frag,P_frag):
// acc cols = Q-row l16, rows = 4 consecutive H-cols -> f32x4 b128 stores.
// Softmax stats stay in (g,r) layout; rescale rebroadcast via shfl (rare).
__global__ __launch_bounds__(256, 2) void attn_kernel(
    const u16 *__restrict__ x1k, const u16 *__restrict__ x2k,
    const u16 *__restrict__ vT, const float *__restrict__ bias,
    float *__restrict__ out) {
  __shared__ u16 K2s[64 * 256]; // 32KB: row j 512B; chunk c at slot c^(j&7)
  __shared__ u16 VTs[256 * 64]; // 32KB: row dd 128B; chunk c at slot c^(dd&7)
  __shared__ float biasS[1024];
  __shared__ u16 P[4][16 * 72]; // per-wave P, row stride 144B (9 chunks)

  const int t = threadIdx.x;
  const int lane = t & 63, wid = t >> 6;
  const int l16 = lane & 15, g = lane >> 4;
  const int id = blockIdx.x; // 0..511
  const int xcd = id & 7, idx = id >> 3;
  const int it = idx & 15, pp = idx >> 4;
  const int pair = xcd + 8 * pp;
  const int b = pair >> 2, m = pair & 3;

  for (int j = t; j < 1024; j += 256) biasS[j] = bias[b * 1024 + j];

  const int qrow = it * 64 + wid * 16 + l16;
  const u16 *qsrc = x1k + ((size_t)b * 1024 + qrow) * 1024 + m * 256;
  u16x8 Q[8];
#pragma unroll
  for (int dk = 0; dk < 8; ++dk) Q[dk] = *(const u16x8 *)(qsrc + dk * 32 + g * 8);

  f32x4 acc[16] = {}; // [nf]: col = Q-row l16, rows = H-col nf*16+g*4+q
  float mrow[4] = {-1e30f, -1e30f, -1e30f, -1e30f};
  float lrow[4] = {0.f, 0.f, 0.f, 0.f};

  const int sj = t >> 2, cb = (t & 3) * 8;
  const u16 *ksrc = x2k + ((size_t)b * 1024 + sj) * 1024 + m * 256 + cb * 8;
  const u16 *vtsrc = vT + ((size_t)((b * 4 + m) * 256 + t)) * 1024;
  uint32_t koff[8], voff[8];
#pragma unroll
  for (int q = 0; q < 8; ++q) {
    koff[q] = sj * 512 + ((uint32_t)((cb + q) ^ (sj & 7)) << 4);
    voff[q] = t * 128 + ((uint32_t)(q ^ (t & 7)) << 4);
  }

  u16x8 pk[8], pv[8];
#pragma unroll
  for (int q = 0; q < 8; ++q) {
    pk[q] = *(const u16x8 *)(ksrc + q * 8);
    pv[q] = *(const u16x8 *)(vtsrc + q * 8);
  }

  for (int jt = 0; jt < 16; ++jt) {
    __syncthreads(); // prev compute done reading LDS
#pragma unroll
    for (int q = 0; q < 8; ++q) {
      *(u16x8 *)((char *)K2s + koff[q]) = pk[q];
      *(u16x8 *)((char *)VTs + voff[q]) = pv[q];
    }
    __syncthreads(); // staging visible
    if (jt < 15) { // prefetch next tile
      const u16 *k2 = ksrc + (size_t)(jt + 1) * 64 * 1024;
      const u16 *v2 = vtsrc + (jt + 1) * 64;
#pragma unroll
      for (int q = 0; q < 8; ++q) {
        pk[q] = *(const u16x8 *)(k2 + q * 8);
        pv[q] = *(const u16x8 *)(v2 + q * 8);
      }
    }

    // QK^T: rows i=g*4+r (Q-rows), cols j = jh*16+l16; 32 MFMA
    f32x4 s[4] = {};
    __builtin_amdgcn_s_setprio(1);
#pragma unroll
    for (int dk = 0; dk < 8; ++dk) {
#pragma unroll
      for (int jh = 0; jh < 4; ++jh) {
        const int j = jh * 16 + l16;
        uint32_t off = j * 512 + ((uint32_t)((dk * 4 + g) ^ (j & 7)) << 4);
        u16x8 kk = *(const u16x8 *)((const char *)K2s + off);
        s[jh] = mfma16h(Q[dk], kk, s[jh]);
      }
    }
    __builtin_amdgcn_s_setprio(0);

    // online softmax with defer-max (stats in (g,r) layout)
    const int j0 = jt * 64;
    float bj[4];
#pragma unroll
    for (int jh = 0; jh < 4; ++jh) bj[jh] = biasS[j0 + jh * 16 + l16];
    float tm[4];
#pragma unroll
    for (int r = 0; r < 4; ++r) {
#pragma unroll
      for (int jh = 0; jh < 4; ++jh) s[jh][r] += bj[jh];
      tm[r] = fmaxf(fmaxf(s[0][r], s[1][r]), fmaxf(s[2][r], s[3][r]));
    }
#pragma unroll
    for (int d = 1; d < 16; d <<= 1)
#pragma unroll
      for (int r = 0; r < 4; ++r) tm[r] = fmaxf(tm[r], __shfl_xor(tm[r], d, 64));
    bool need = false;
#pragma unroll
    for (int r = 0; r < 4; ++r)
      need = need || ((tm[r] - mrow[r]) * L2E > DEFER_THR);
    if (__any((int)need)) {
      float scv[4];
#pragma unroll
      for (int r = 0; r < 4; ++r) {
        float nm = fmaxf(mrow[r], tm[r]);
        scv[r] = exp2f((mrow[r] - nm) * L2E);
        mrow[r] = nm;
        lrow[r] *= scv[r];
      }
      // rebroadcast: factor for Q-row l16 lives in g-group l16>>2, slot l16&3
      const int src = ((l16 >> 2) << 4) + l16;
      float s0b = __shfl(scv[0], src, 64), s1b = __shfl(scv[1], src, 64);
      float s2b = __shfl(scv[2], src, 64), s3b = __shfl(scv[3], src, 64);
      float scR = (l16 & 2) ? ((l16 & 1) ? s3b : s2b)
                            : ((l16 & 1) ? s1b : s0b);
#pragma unroll
      for (int nf = 0; nf < 16; ++nf)
#pragma unroll
        for (int q = 0; q < 4; ++q) acc[nf][q] *= scR;
    }
    float p[4][4], rs[4];
#pragma unroll
    for (int r = 0; r < 4; ++r) {
#pragma unroll
      for (int jh = 0; jh < 4; ++jh) p[jh][r] = exp2f((s[jh][r] - mrow[r]) * L2E);
      rs[r] = (p[0][r] + p[1][r]) + (p[2][r] + p[3][r]);
    }
#pragma unroll
    for (int d = 1; d < 16; d <<= 1)
#pragma unroll
      for (int r = 0; r < 4; ++r) rs[r] += __shfl_xor(rs[r], d, 64);
#pragma unroll
    for (int r = 0; r < 4; ++r) lrow[r] += rs[r];

    // P -> per-wave LDS (fp16), then PV (32 MFMA, swapped: A=V^T, B=P)
    u16 *Pw = &P[wid][0];
#pragma unroll
    for (int jh = 0; jh < 4; ++jh)
#pragma unroll
      for (int r = 0; r < 4; ++r)
        Pw[(g * 4 + r) * 72 + jh * 16 + l16] = f2h(p[jh][r]);
    u16x8 pa[2];
#pragma unroll
    for (int kk = 0; kk < 2; ++kk)
      pa[kk] = *(const u16x8 *)(Pw + l16 * 72 + kk * 32 + g * 8);
    __builtin_amdgcn_s_setprio(1);
#pragma unroll
    for (int nf = 0; nf < 16; ++nf) {
      const int dd = nf * 16 + l16;
#pragma unroll
      for (int kk = 0; kk < 2; ++kk) {
        uint32_t off = dd * 128 + ((uint32_t)((kk * 4 + g) ^ (dd & 7)) << 4);
        u16x8 bb = *(const u16x8 *)((const char *)VTs + off);
        acc[nf] = mfma16h(bb, pa[kk], acc[nf]); // D rows = H-cols, cols = Q-row
      }
    }
    __builtin_amdgcn_s_setprio(0);
  }

  // final 1/l rebroadcast to Q-row = l16 layout, then b128 stores
  float linv[4];
#pragma unroll
  for (int r = 0; r < 4; ++r) linv[r] = 1.0f / lrow[r];
  const int src = ((l16 >> 2) << 4) + l16;
  float i0 = __shfl(linv[0], src, 64), i1 = __shfl(linv[1], src, 64);
  float i2 = __shfl(linv[2], src, 64), i3 = __shfl(linv[3], src, 64);
  const float invR = (l16 & 2) ? ((l16 & 1) ? i3 : i2) : ((l16 & 1) ? i1 : i0);
  const int row = it * 64 + wid * 16 + l16;
#pragma unroll
  for (int nf = 0; nf < 16; ++nf) {
    const int col = m * 256 + nf * 16 + g * 4;
    f32x4 o;
#pragma unroll
    for (int q = 0; q < 4; ++q) o[q] = acc[nf][q] * invR;
    *(f32x4 *)(out + ((size_t)b * 1024 + row) * 1024 + col) = o;
  }
}

// ---------------- launch ----------------------------------------------------
extern "C" void kernel_launch(void *const *d_in, const int *in_sizes, int n_in,
                              void *d_out, int out_size, void *d_ws,
                              size_t ws_size, hipStream_t stream) {
  const float *x1_att = (const float *)d_in[0];
  const float *x2_att = (const float *)d_in[1];
  const float *x2 = (const float *)d_in[2];
  const unsigned char *mask = (const unsigned char *)d_in[3];
  const float *W = (const float *)d_in[4];
  const float *fv = (const float *)d_in[5];
  float *out = (float *)d_out;

  const size_t MB = 1u << 20;
  char *ws = (char *)d_ws;
  u16 *x1a16 = (u16 *)(ws + 0 * MB);     // 16MB
  u16 *x2a16 = (u16 *)(ws + 16 * MB);    // 16MB
  u16 *W16 = (u16 *)(ws + 32 * MB);      // 2MB
  u16 *x1k = (u16 *)(ws + 34 * MB);      // 16MB
  u16 *x2k = (u16 *)(ws + 50 * MB);      // 16MB
  u16 *vT = (u16 *)(ws + 66 * MB);       // 16MB
  float *bias = (float *)(ws + 82 * MB); // 32KB

  prep_mask_kernel<<<dim3(1), dim3(256), 0, stream>>>(mask, bias);
  cvt_f16_kernel<<<dim3(4096), dim3(256), 0, stream>>>(x1_att, x1a16);
  cvt_f16_kernel<<<dim3(4096), dim3(256), 0, stream>>>(x2_att, x2a16);
  cvt_f16_kernel<<<dim3(512), dim3(256), 0, stream>>>(W, W16);
  proj_kernel<<<dim3(64, 8), dim3(256), 0, stream>>>(x1a16, W16, fv, x1k, 0);
  proj_kernel<<<dim3(64, 8), dim3(256), 0, stream>>>(x2a16, W16, fv, x2k, 1);
  transpose_v_kernel<<<dim3(32, 32, 8), dim3(256), 0, stream>>>(x2, vT);
  attn_kernel<<<dim3(512), dim3(256), 0, stream>>>(x1k, x2k, vT, bias, out);
}